// Round 16
// baseline (3096.645 us; speedup 1.0000x reference)
//
#include <hip/hip_runtime.h>
#include <hip/hip_cooperative_groups.h>
#include <stdint.h>

namespace cg = cooperative_groups;

#define NB   32
#define NC   256
#define NPTS 4096
#define KCL  8
#define KC   384          // OpenBLAS sgemm KC panel
#define NPANEL 11         // 10*384 + 256
#define HALF0 192         // psum staged half size
#define BSTR  196         // psum buf row stride (floats)
#define NUNIT (NB*NPANEL*KCL)   // 2816 psum units

// ---- numpy npyv AVX512 pairwise sum-of-squares (r6-verified bits) ----
__device__ __forceinline__ float np_sumsq_avx512(const float* sh) {
  float half[2];
  #pragma unroll
  for (int h = 0; h < 2; ++h) {
    const float* ap = sh + h * 128;
    float rv[16];
    #pragma unroll
    for (int l = 0; l < 16; ++l) {
      float q[8];
      #pragma unroll
      for (int j = 0; j < 8; ++j) {
        float e = ap[16 * j + l];
        q[j] = __fmul_rn(e, e);
      }
      rv[l] = __fadd_rn(__fadd_rn(__fadd_rn(q[0], q[1]), __fadd_rn(q[2], q[3])),
                        __fadd_rn(__fadd_rn(q[4], q[5]), __fadd_rn(q[6], q[7])));
    }
    float t1[8];
    #pragma unroll
    for (int l = 0; l < 8; ++l) t1[l] = __fadd_rn(rv[l], rv[l + 8]);
    float t2[4];
    #pragma unroll
    for (int l = 0; l < 4; ++l) t2[l] = __fadd_rn(t1[l], t1[l + 2 + 2]);
    float t3[2];
    #pragma unroll
    for (int l = 0; l < 2; ++l) t3[l] = __fadd_rn(t2[l], t2[l + 2]);
    half[h] = __fadd_rn(t3[0], t3[1]);
  }
  return __fadd_rn(half[0], half[1]);
}

// same tree, elements at base[i*KCL + k] (centL is [c][k]) — r13-verified
__device__ __forceinline__ float np_sumsq_avx512_s8(const float* base, int k) {
  float half[2];
  #pragma unroll
  for (int h = 0; h < 2; ++h) {
    float rv[16];
    #pragma unroll
    for (int l = 0; l < 16; ++l) {
      float q[8];
      #pragma unroll
      for (int j = 0; j < 8; ++j) {
        float e = base[(h * 128 + 16 * j + l) * KCL + k];
        q[j] = __fmul_rn(e, e);
      }
      rv[l] = __fadd_rn(__fadd_rn(__fadd_rn(q[0], q[1]), __fadd_rn(q[2], q[3])),
                        __fadd_rn(__fadd_rn(q[4], q[5]), __fadd_rn(q[6], q[7])));
    }
    float t1[8];
    #pragma unroll
    for (int l = 0; l < 8; ++l) t1[l] = __fadd_rn(rv[l], rv[l + 8]);
    float t2[4];
    #pragma unroll
    for (int l = 0; l < 4; ++l) t2[l] = __fadd_rn(t1[l], t1[l + 2 + 2]);
    float t3[2];
    #pragma unroll
    for (int l = 0; l < 2; ++l) t3[l] = __fadd_rn(t2[l], t2[l + 2]);
    half[h] = __fadd_rn(t3[0], t3[1]);
  }
  return __fadd_rn(half[0], half[1]);
}

// ---------------- init: centroids(cent0) = first 8 points ----------------
__global__ __launch_bounds__(256) void k_init(const float* __restrict__ X,
                                              float* __restrict__ cent0,
                                              float* __restrict__ cnorm0) {
  const int b = blockIdx.x >> 3, k = blockIdx.x & 7, c = threadIdx.x;
  __shared__ float sarr[NC];
  float v = X[(size_t)b * NC * NPTS + (size_t)c * NPTS + k];
  cent0[(b * NC + c) * KCL + k] = v;
  sarr[c] = v;
  __syncthreads();
  if (c == 0) cnorm0[b * KCL + k] = np_sumsq_avx512(sarr);
}

// ======== A-phase body: combine prologue + direct-read labels (r13 bits) ====
__device__ __forceinline__ void assign_body(
    const float* __restrict__ X, const float* __restrict__ pp,
    const int* __restrict__ pc, const float* __restrict__ centPrev,
    float* __restrict__ centCur, const float* __restrict__ cnorm0,
    int* __restrict__ lab, int it, int b, int n0, int t,
    float* centL, float* cnfL) {
  if (it == 0) {
    const float4* cp = (const float4*)(centPrev + (size_t)b * NC * KCL);
    #pragma unroll
    for (int i2 = 0; i2 < 2; ++i2)
      ((float4*)centL)[i2 * 256 + t] = cp[i2 * 256 + t];
    if (t < KCL) cnfL[t] = cnorm0[b * KCL + t];
  } else {
    const int c = t;
    #pragma unroll
    for (int k = 0; k < KCL; ++k) {
      float C = 0.f; int cnt = 0;
      for (int pnl = 0; pnl < NPANEL; ++pnl) {
        C = __fadd_rn(C, pp[(size_t)((b * NPANEL + pnl) * KCL + k) * NC + c]);
        cnt += pc[(b * NPANEL + pnl) * KCL + k];
      }
      const float mean = __fdiv_rn(C, (float)((cnt > 0) ? cnt : 1));
      const int ci = (b * NC + c) * KCL + k;
      float nv = (cnt > 0) ? mean : centPrev[ci];
      centCur[ci] = nv;                 // duplicate identical writes: benign
      centL[c * KCL + k] = nv;
    }
    __syncthreads();
    if (t < KCL) cnfL[t] = np_sumsq_avx512_s8(centL, t);
  }
  __syncthreads();

  float cnf[KCL];
  #pragma unroll
  for (int k = 0; k < KCL; ++k) cnf[k] = cnfL[k];

  const float* Xp = X + (size_t)b * NC * NPTS + n0 + t;
  const float4* cL4 = (const float4*)centL;
  float a = 0.f;
  float bb[KCL];
  #pragma unroll
  for (int k = 0; k < KCL; ++k) bb[k] = 0.f;

  #pragma unroll 8
  for (int c = 0; c < NC; ++c) {
    float x = Xp[(size_t)c * NPTS];      // lanes consecutive -> coalesced
    a = __fadd_rn(a, __fmul_rn(x, x));
    float4 c0 = cL4[c * 2], c1 = cL4[c * 2 + 1];
    bb[0] = __builtin_fmaf(x, c0.x, bb[0]);
    bb[1] = __builtin_fmaf(x, c0.y, bb[1]);
    bb[2] = __builtin_fmaf(x, c0.z, bb[2]);
    bb[3] = __builtin_fmaf(x, c0.w, bb[3]);
    bb[4] = __builtin_fmaf(x, c1.x, bb[4]);
    bb[5] = __builtin_fmaf(x, c1.y, bb[5]);
    bb[6] = __builtin_fmaf(x, c1.z, bb[6]);
    bb[7] = __builtin_fmaf(x, c1.w, bb[7]);
  }

  int lb = 0; float best = 3.4e38f;
  #pragma unroll
  for (int k = 0; k < KCL; ++k) {
    float d = __fadd_rn(__fsub_rn(a, __fmul_rn(2.0f, bb[k])), cnf[k]);
    if (d < best) { best = d; lb = k; }
  }
  lab[b * NPTS + n0 + t] = lb;
}

// ======== P-phase body: half-staged member-only chains (r13 bits) ===========
__device__ __forceinline__ void psum_body(
    const float* __restrict__ X, const int* __restrict__ lab,
    float* __restrict__ pp, int* __restrict__ pc,
    int b, int panel, int cg, int t,
    float* buf, int* perm, int (*wcnt)[KCL], int (*cbase)[KCL],
    int* offs, int* hist) {
  const int p0 = panel * KC;
  const int len = (panel < 10) ? KC : (NPTS - 10 * KC);   // 384 or 256
  const int k = t & 7, cl = t >> 3, lane = t & 63;

  const float* Xb = X + (size_t)b * NC * NPTS + (size_t)(cg * 32) * NPTS + p0;

  // ---- stage half0: 192 pts (always full) ----
  #pragma unroll
  for (int i2 = 0; i2 < 6; ++i2) {
    int i = i2 * 256 + t;
    int c = i / 48, q4 = i - c * 48;
    *(float4*)&buf[c * BSTR + q4 * 4] =
        *(const float4*)(Xb + (size_t)c * NPTS + q4 * 4);
  }

  // ---- ballot counting sort over full panel (labels only) ----
  const int* Lb = lab + b * NPTS + p0;
  const uint64_t lt = (1ull << lane) - 1ull;
  int ml0, ml1, rk0 = 0, rk1 = 0;
  {
    const int q = t;                 // chunks 0..3
    ml0 = (q < len) ? Lb[q] : -1;
    const int chunk = q >> 6;
    #pragma unroll
    for (int kk = 0; kk < KCL; ++kk) {
      uint64_t m = __ballot(ml0 == kk);
      if (lane == 0) wcnt[chunk][kk] = (int)__popcll(m);
      if (ml0 == kk) rk0 = (int)__popcll(m & lt);
    }
  }
  {
    const int q = 256 + t;           // chunks 4..7 (6,7 guarded)
    ml1 = (q < len) ? Lb[q] : -1;
    const int chunk = q >> 6;
    #pragma unroll
    for (int kk = 0; kk < KCL; ++kk) {
      uint64_t m = __ballot(ml1 == kk);
      if (lane == 0 && chunk < 6) wcnt[chunk][kk] = (int)__popcll(m);
      if (ml1 == kk) rk1 = (int)__popcll(m & lt);
    }
  }
  __syncthreads();
  if (t == 0) {
    int rr = 0;
    for (int kk = 0; kk < KCL; ++kk) {
      int s = 0;
      #pragma unroll
      for (int ch = 0; ch < 6; ++ch) { cbase[ch][kk] = rr + s; s += wcnt[ch][kk]; }
      offs[kk] = rr; hist[kk] = s; rr += s;
    }
  }
  __syncthreads();
  if (ml0 >= 0) perm[cbase[t >> 6][ml0] + rk0] = t;
  if (ml1 >= 0) perm[cbase[(256 + t) >> 6][ml1] + rk1] = 256 + t;
  __syncthreads();

  // ---- chain half0: members with p < 192, ascending ----
  const int base = offs[k], n = hist[k];
  const int nh0 = cbase[3][k] - offs[k];
  const float* bp = &buf[cl * BSTR];
  float pa = 0.f;
  #pragma unroll 4
  for (int i = 0; i < nh0; ++i) {
    int p = perm[base + i];
    pa = __fadd_rn(pa, bp[p]);
  }
  __syncthreads();          // all chain-h0 reads done before overwrite

  // ---- stage half1: len-192 pts (192 or 64) ----
  const int nf4 = (len - HALF0) >> 2;         // 48 or 16
  #pragma unroll
  for (int i2 = 0; i2 < 6; ++i2) {
    int i = i2 * 256 + t;
    int c = i / 48, q4 = i - c * 48;
    if (q4 < nf4)
      *(float4*)&buf[c * BSTR + q4 * 4] =
          *(const float4*)(Xb + (size_t)c * NPTS + HALF0 + q4 * 4);
  }
  __syncthreads();

  // ---- chain half1: continue same pa, same ascending order ----
  #pragma unroll 4
  for (int i = nh0; i < n; ++i) {
    int p = perm[base + i] - HALF0;
    pa = __fadd_rn(pa, bp[p]);
  }
  pp[(size_t)((b * NPANEL + panel) * KCL + k) * NC + cg * 32 + cl] = pa;
  if (cl == 0) pc[(b * NPANEL + panel) * KCL + k] = n;
}

// ======== out body (r11 verbatim bits) ========
__device__ __forceinline__ void out_body(const float* __restrict__ pp,
                                         const int* __restrict__ pc,
                                         float* __restrict__ out,
                                         int b, int k, int c) {
  float C = 0.f;
  int cnt = 0;
  for (int pnl = 0; pnl < NPANEL; ++pnl) {
    C = __fadd_rn(C, pp[(size_t)((b * NPANEL + pnl) * KCL + k) * NC + c]);
    cnt += pc[(b * NPANEL + pnl) * KCL + k];
  }
  out[(b * KCL + k) * NC + c] =
      (cnt > 0) ? __fdiv_rn(C, (float)cnt) : 0.0f;
}

// ---------------- standalone kernels (fallback path) ----------------
__global__ __launch_bounds__(256) void k_assign(const float* __restrict__ X,
                                                const float* __restrict__ pp,
                                                const int* __restrict__ pc,
                                                const float* __restrict__ centPrev,
                                                float* __restrict__ centCur,
                                                const float* __restrict__ cnorm0,
                                                int* __restrict__ lab,
                                                int it) {
  __shared__ __align__(16) float centL[NC * KCL];
  __shared__ float cnfL[KCL];
  const int blk = blockIdx.x;
  assign_body(X, pp, pc, centPrev, centCur, cnorm0, lab, it,
              blk >> 4, (blk & 15) << 8, threadIdx.x, centL, cnfL);
}

__global__ __launch_bounds__(256) void k_psum(const float* __restrict__ X,
                                              const int* __restrict__ lab,
                                              float* __restrict__ pp,
                                              int* __restrict__ pc) {
  __shared__ __align__(16) float buf[32 * BSTR];
  __shared__ int perm[KC];
  __shared__ int wcnt[6][KCL], cbase[6][KCL], offs[KCL], hist[KCL];
  const int blk = blockIdx.x;
  const int b = blk / 88, r = blk % 88;
  psum_body(X, lab, pp, pc, b, r >> 3, r & 7, threadIdx.x,
            buf, perm, wcnt, cbase, offs, hist);
}

__global__ __launch_bounds__(256) void k_out(const float* __restrict__ pp,
                                             const int* __restrict__ pc,
                                             float* __restrict__ out) {
  out_body(pp, pc, out, blockIdx.x >> 3, blockIdx.x & 7, threadIdx.x);
}

// ---------------- cooperative persistent kernel ----------------
__global__ __launch_bounds__(256, 2) void k_all(const float* __restrict__ X,
                                                float* __restrict__ cent0,
                                                float* __restrict__ cent1,
                                                const float* __restrict__ cnorm0,
                                                int* __restrict__ lab,
                                                float* __restrict__ pp,
                                                int* __restrict__ pc,
                                                float* __restrict__ out) {
  cg::grid_group grid = cg::this_grid();
  const int bid = blockIdx.x, t = threadIdx.x;

  __shared__ __align__(16) float centL[NC * KCL];   // 8 KB
  __shared__ float cnfL[KCL];
  __shared__ __align__(16) float buf[32 * BSTR];    // 24.5 KB
  __shared__ int perm[KC];
  __shared__ int wcnt[6][KCL], cbase[6][KCL], offs[KCL], hist[KCL];

  const int bA = bid >> 4, n0 = (bid & 15) << 8;    // A-phase tile (r13 map)
  float* cent[2] = {cent0, cent1};

  for (int it = 0; it <= 10; ++it) {
    const float* prev = (it <= 1) ? cent0 : cent[(it - 1) & 1];
    float* cur = (it == 0) ? cent1 : cent[it & 1];
    assign_body(X, pp, pc, prev, cur, cnorm0, lab, it, bA, n0, t, centL, cnfL);
    grid.sync();
    for (int u = bid; u < NUNIT; u += 512) {
      int b = u / 88, r = u % 88;
      psum_body(X, lab, pp, pc, b, r >> 3, r & 7, t,
                buf, perm, wcnt, cbase, offs, hist);
      __syncthreads();       // buf/perm reuse across units
    }
    grid.sync();
  }
  if (bid < NB * KCL) out_body(pp, pc, out, bid >> 3, bid & 7, t);
}

extern "C" void kernel_launch(void* const* d_in, const int* in_sizes, int n_in,
                              void* d_out, int out_size, void* d_ws, size_t ws_size,
                              hipStream_t stream) {
  const float* X = (const float*)d_in[0];
  float* out = (float*)d_out;

  // ws: cent0 | cent1 | cnorm0 | lab | pp | pc    (~4.1 MB)
  float* cent0  = (float*)d_ws;
  float* cent1  = cent0 + (size_t)NB * NC * KCL;
  float* cnorm0 = cent1 + (size_t)NB * NC * KCL;
  int*   lab    = (int*)(cnorm0 + NB * KCL);
  float* pp     = (float*)(lab + (size_t)NB * NPTS);
  int*   pc     = (int*)(pp + (size_t)NB * NPANEL * KCL * NC);

  k_init<<<NB * KCL, 256, 0, stream>>>(X, cent0, cnorm0);

  const float* Xa = X;
  float* c0a = cent0; float* c1a = cent1; const float* cna = cnorm0;
  int* laba = lab; float* ppa = pp; int* pca = pc; float* outa = out;
  void* args[] = {&Xa, &c0a, &c1a, &cna, &laba, &ppa, &pca, &outa};
  hipError_t e = hipLaunchCooperativeKernel((void*)k_all, dim3(512), dim3(256),
                                            args, 0, stream);
  if (e != hipSuccess) {
    // fallback: proven r13 sequence
    float* cent[2] = {cent0, cent1};
    for (int it = 0; it <= 10; ++it) {
      const float* prev = (it <= 1) ? cent0 : cent[(it - 1) & 1];
      float* cur = (it == 0) ? cent1 : cent[it & 1];
      k_assign<<<NB * 16, 256, 0, stream>>>(X, pp, pc, prev, cur, cnorm0, lab, it);
      k_psum<<<NB * NPANEL * KCL, 256, 0, stream>>>(X, lab, pp, pc);
    }
    k_out<<<NB * KCL, 256, 0, stream>>>(pp, pc, out);
  }
}

// Round 17
// 742.411 us; speedup vs baseline: 4.1711x; 4.1711x over previous
//
#include <hip/hip_runtime.h>
#include <stdint.h>

#define NB   32
#define NC   256
#define NPTS 4096
#define KCL  8
#define KC   384          // OpenBLAS sgemm KC panel
#define NPANEL 11         // 10*384 + 256
#define BSTRIDE 388       // buf row stride (floats): 16B-aligned, read-spread

// Contiguous-axis pairwise, numpy npyv SIMD path on AVX512 (nlanes=16):
// used for ||cent||^2. KEEP BIT-IDENTICAL to r6 (incl. the l+2+2 quirk).
__device__ float np_sumsq_avx512(const float* sh) {
  float half[2];
  #pragma unroll
  for (int h = 0; h < 2; ++h) {
    const float* ap = sh + h * 128;
    float rv[16];
    #pragma unroll
    for (int l = 0; l < 16; ++l) {
      float q[8];
      #pragma unroll
      for (int j = 0; j < 8; ++j) {
        float e = ap[16 * j + l];
        q[j] = __fmul_rn(e, e);
      }
      rv[l] = __fadd_rn(__fadd_rn(__fadd_rn(q[0], q[1]), __fadd_rn(q[2], q[3])),
                        __fadd_rn(__fadd_rn(q[4], q[5]), __fadd_rn(q[6], q[7])));
    }
    float t1[8];
    #pragma unroll
    for (int l = 0; l < 8; ++l) t1[l] = __fadd_rn(rv[l], rv[l + 8]);
    float t2[4];
    #pragma unroll
    for (int l = 0; l < 4; ++l) t2[l] = __fadd_rn(t1[l], t1[l + 2 + 2]);
    float t3[2];
    #pragma unroll
    for (int l = 0; l < 2; ++l) t3[l] = __fadd_rn(t2[l], t2[l + 2]);
    half[h] = __fadd_rn(t3[0], t3[1]);
  }
  return __fadd_rn(half[0], half[1]);
}

// ---------------- init: centroids = first 8 points ----------------
__global__ __launch_bounds__(256) void k_init(const float* __restrict__ X,
                                              float* __restrict__ centT,
                                              float* __restrict__ cnorm) {
  const int b = blockIdx.x >> 3, k = blockIdx.x & 7, c = threadIdx.x;
  __shared__ float sarr[NC];
  float v = X[(size_t)b * NC * NPTS + (size_t)c * NPTS + k];
  centT[(b * NC + c) * KCL + k] = v;
  sarr[c] = v;
  __syncthreads();
  if (c == 0) cnorm[b * KCL + k] = np_sumsq_avx512(sarr);
}

// -------- assign: no LDS, direct coalesced reads (r9/r10/r11-proven bits) ----
__global__ __launch_bounds__(256) void k_assign(const float* __restrict__ X,
                                                const float* __restrict__ centT,
                                                const float* __restrict__ cnorm,
                                                int* __restrict__ lab) {
  const int blk = blockIdx.x;            // 512 = 32 b * 16 tiles
  const int b   = blk >> 4;
  const int n0  = (blk & 15) << 8;
  const int t   = threadIdx.x;

  const float* Xp = X + (size_t)b * NC * NPTS + n0 + t;
  const float4* cw = (const float4*)(centT + (size_t)b * NC * KCL); // uniform

  float cnf[KCL];
  #pragma unroll
  for (int k = 0; k < KCL; ++k) cnf[k] = cnorm[b * KCL + k];

  float a = 0.f;
  float bb[KCL];
  #pragma unroll
  for (int k = 0; k < KCL; ++k) bb[k] = 0.f;

  #pragma unroll 8
  for (int c = 0; c < NC; ++c) {
    float x = Xp[(size_t)c * NPTS];      // lanes consecutive -> coalesced
    a = __fadd_rn(a, __fmul_rn(x, x));
    float4 c0 = cw[c * 2], c1 = cw[c * 2 + 1];
    bb[0] = __builtin_fmaf(x, c0.x, bb[0]);
    bb[1] = __builtin_fmaf(x, c0.y, bb[1]);
    bb[2] = __builtin_fmaf(x, c0.z, bb[2]);
    bb[3] = __builtin_fmaf(x, c0.w, bb[3]);
    bb[4] = __builtin_fmaf(x, c1.x, bb[4]);
    bb[5] = __builtin_fmaf(x, c1.y, bb[5]);
    bb[6] = __builtin_fmaf(x, c1.z, bb[6]);
    bb[7] = __builtin_fmaf(x, c1.w, bb[7]);
  }

  int lb = 0; float best = 3.4e38f;
  #pragma unroll
  for (int k = 0; k < KCL; ++k) {
    float d = __fadd_rn(__fsub_rn(a, __fmul_rn(2.0f, bb[k])), cnf[k]);
    if (d < best) { best = d; lb = k; }
  }
  lab[b * NPTS + n0 + t] = lb;
}

// ---- per-panel partial sums: counting-sort + member-only ordered chains ----
// block = (b, panel, cg): 2816 blocks. threads: k = t&7, cl = t>>3.
// Fold sequence per (k,channel) is ascending point order within the panel —
// bit-identical to r10's conditional walk.
__global__ __launch_bounds__(256) void k_psum(const float* __restrict__ X,
                                              const int* __restrict__ lab,
                                              float* __restrict__ pp,
                                              int* __restrict__ pc) {
  const int blk = blockIdx.x;
  const int b = blk / 88, r = blk % 88, panel = r >> 3, cg = r & 7;
  const int p0 = panel * KC;
  const int len = (panel < 10) ? KC : (NPTS - 10 * KC);   // 384 or 256
  const int t = threadIdx.x, k = t & 7, cl = t >> 3, lane = t & 63;

  __shared__ __align__(16) float buf[32 * BSTRIDE];  // 49.7 KB, [ch][pt]
  __shared__ int perm[KC];
  __shared__ int wcnt[6][KCL];       // per-64-chunk, per-k counts
  __shared__ int cbase[6][KCL];      // chunk base offset within cluster list
  __shared__ int offs[KCL], hist[KCL];

  // ---- stage: float4 global -> float4 LDS, conflict-free ----
  const float* Xb = X + (size_t)b * NC * NPTS + (size_t)(cg * 32) * NPTS + p0;
  if (len == KC) {
    #pragma unroll
    for (int i2 = 0; i2 < 12; ++i2) {            // 32ch * 96 p4 / 256
      int i = i2 * 256 + t;
      int c = i / 96, q4 = i - c * 96;
      float4 v = *(const float4*)(Xb + (size_t)c * NPTS + q4 * 4);
      *(float4*)&buf[c * BSTRIDE + q4 * 4] = v;
    }
  } else {
    #pragma unroll
    for (int i2 = 0; i2 < 8; ++i2) {             // 32ch * 64 p4 / 256
      int i = i2 * 256 + t;
      int c = i >> 6, q4 = i & 63;
      float4 v = *(const float4*)(Xb + (size_t)c * NPTS + q4 * 4);
      *(float4*)&buf[c * BSTRIDE + q4 * 4] = v;
    }
  }

  // ---- ballot counting sort (stable, ascending point order) ----
  const int* Lb = lab + b * NPTS + p0;
  const uint64_t lt = (1ull << lane) - 1ull;
  int ml0, ml1, rk0 = 0, rk1 = 0;
  {
    const int q = t;                 // chunk = t>>6 in 0..3
    ml0 = (q < len) ? Lb[q] : -1;
    const int chunk = q >> 6;
    #pragma unroll
    for (int kk = 0; kk < KCL; ++kk) {
      uint64_t m = __ballot(ml0 == kk);
      if (lane == 0) wcnt[chunk][kk] = (int)__popcll(m);
      if (ml0 == kk) rk0 = (int)__popcll(m & lt);
    }
  }
  {
    const int q = 256 + t;           // chunk in 4..7 (6,7 invalid & guarded)
    ml1 = (q < len) ? Lb[q] : -1;
    const int chunk = q >> 6;
    #pragma unroll
    for (int kk = 0; kk < KCL; ++kk) {
      uint64_t m = __ballot(ml1 == kk);
      if (lane == 0 && chunk < 6) wcnt[chunk][kk] = (int)__popcll(m);
      if (ml1 == kk) rk1 = (int)__popcll(m & lt);
    }
  }
  __syncthreads();
  if (t == 0) {
    int rr = 0;
    for (int kk = 0; kk < KCL; ++kk) {
      int s = 0;
      #pragma unroll
      for (int ch = 0; ch < 6; ++ch) { cbase[ch][kk] = rr + s; s += wcnt[ch][kk]; }
      offs[kk] = rr; hist[kk] = s; rr += s;
    }
  }
  __syncthreads();
  if (ml0 >= 0) perm[cbase[t >> 6][ml0] + rk0] = t;
  if (ml1 >= 0) perm[cbase[(256 + t) >> 6][ml1] + rk1] = 256 + t;
  __syncthreads();

  // ---- member-only ordered chain: n_k dependent fadds (not 384) ----
  const int base = offs[k], n = hist[k];
  const float* bp = &buf[cl * BSTRIDE];
  float pa = 0.f;
  #pragma unroll 4
  for (int i = 0; i < n; ++i) {
    int p = perm[base + i];          // broadcast per k
    pa = __fadd_rn(pa, bp[p]);
  }
  pp[(size_t)((b * NPANEL + panel) * KCL + k) * NC + cg * 32 + cl] = pa;
  if (cl == 0) pc[(b * NPANEL + panel) * KCL + k] = n;
}

// ---------------- ordered panel combine -> centroids + cnorm (r6 verbatim) ----
__global__ __launch_bounds__(256) void k_combine(const float* __restrict__ pp,
                                                 const int* __restrict__ pc,
                                                 float* __restrict__ centT,
                                                 float* __restrict__ cnorm) {
  const int b = blockIdx.x >> 3, k = blockIdx.x & 7, c = threadIdx.x;
  float C = 0.f;          // 0 + x exact: ordered fold == BLAS C-update
  int cnt = 0;
  for (int pnl = 0; pnl < NPANEL; ++pnl) {
    C = __fadd_rn(C, pp[(size_t)((b * NPANEL + pnl) * KCL + k) * NC + c]);
    cnt += pc[(b * NPANEL + pnl) * KCL + k];
  }
  const float mean = __fdiv_rn(C, (float)((cnt > 0) ? cnt : 1));
  const int ci = (b * NC + c) * KCL + k;
  float nv = (cnt > 0) ? mean : centT[ci];
  centT[ci] = nv;
  __shared__ float sarr[NC];
  sarr[c] = nv;
  __syncthreads();
  if (c == 0) cnorm[b * KCL + k] = np_sumsq_avx512(sarr);
}

// ---------------- final output: fold panels -> means ----------------
__global__ __launch_bounds__(256) void k_out(const float* __restrict__ pp,
                                             const int* __restrict__ pc,
                                             float* __restrict__ out) {
  const int b = blockIdx.x >> 3, k = blockIdx.x & 7, c = threadIdx.x;
  float C = 0.f;
  int cnt = 0;
  for (int pnl = 0; pnl < NPANEL; ++pnl) {
    C = __fadd_rn(C, pp[(size_t)((b * NPANEL + pnl) * KCL + k) * NC + c]);
    cnt += pc[(b * NPANEL + pnl) * KCL + k];
  }
  out[(b * KCL + k) * NC + c] =
      (cnt > 0) ? __fdiv_rn(C, (float)cnt) : 0.0f;
}

extern "C" void kernel_launch(void* const* d_in, const int* in_sizes, int n_in,
                              void* d_out, int out_size, void* d_ws, size_t ws_size,
                              hipStream_t stream) {
  const float* X = (const float*)d_in[0];
  float* out = (float*)d_out;

  // ws: centT f[32*256*8] | cnorm f[32*8] | lab i[32*4096] |
  //     pp f[32*11*8*256] | pc i[32*11*8]     (~3.7 MB)
  float* centT = (float*)d_ws;
  float* cnorm = centT + (size_t)NB * NC * KCL;
  int*   lab   = (int*)(cnorm + NB * KCL);
  float* pp    = (float*)(lab + (size_t)NB * NPTS);
  int*   pc    = (int*)(pp + (size_t)NB * NPANEL * KCL * NC);

  k_init<<<NB * KCL, 256, 0, stream>>>(X, centT, cnorm);
  for (int it = 0; it < 10; ++it) {
    k_assign<<<NB * 16, 256, 0, stream>>>(X, centT, cnorm, lab);
    k_psum<<<NB * NPANEL * KCL, 256, 0, stream>>>(X, lab, pp, pc);
    k_combine<<<NB * KCL, 256, 0, stream>>>(pp, pc, centT, cnorm);
  }
  k_assign<<<NB * 16, 256, 0, stream>>>(X, centT, cnorm, lab);
  k_psum<<<NB * NPANEL * KCL, 256, 0, stream>>>(X, lab, pp, pc);
  k_out<<<NB * KCL, 256, 0, stream>>>(pp, pc, out);
}